// Round 10
// baseline (74.585 us; speedup 1.0000x reference)
//
#include <hip/hip_runtime.h>
#include <cstdint>
#include <cstddef>

typedef float  f32x4   __attribute__((ext_vector_type(4)));
typedef short  bf16x8  __attribute__((ext_vector_type(8)));
typedef unsigned short u16x8 __attribute__((ext_vector_type(8)));

#define L_SEQ   8192
#define D_DIM   1024
#define N_COL   2048
#define N_PAIR  512
#define CHUNK_T 16
#define N_CHUNK 512

__device__ __forceinline__ unsigned short f2bf(float f) {
  unsigned int b = __float_as_uint(f);
  b += 0x7FFFu + ((b >> 16) & 1u);
  return (unsigned short)(b >> 16);
}
__device__ __forceinline__ float bf2f(unsigned short u) {
  return __uint_as_float((unsigned int)u << 16);
}
__device__ __forceinline__ void gload_lds16(const void* g, void* lds) {
  __builtin_amdgcn_global_load_lds(
      (const __attribute__((address_space(1))) void*)g,
      (__attribute__((address_space(3))) void*)lds, 16, 0, 0);
}
__device__ __forceinline__ float2 cmul(float2 a, float2 b) {
  return make_float2(a.x * b.x - a.y * b.y, a.x * b.y + a.y * b.x);
}
__device__ __forceinline__ float2 csqr(float2 a) {
  return make_float2(a.x * a.x - a.y * a.y, 2.f * a.x * a.y);
}
__device__ __forceinline__ void cfma2(const float4& lm, float2& h0, float2& h1,
                                      const float4& v) {
  float nr0 = fmaf(lm.x, h0.x, fmaf(-lm.y, h0.y, v.x));
  float ni0 = fmaf(lm.x, h0.y, fmaf(lm.y, h0.x, v.y));
  float nr1 = fmaf(lm.z, h1.x, fmaf(-lm.w, h1.y, v.z));
  float ni1 = fmaf(lm.z, h1.y, fmaf(lm.w, h1.x, v.w));
  h0.x = nr0; h0.y = ni0; h1.x = nr1; h1.y = ni1;
}

// ---------- K1: fused prep ----------
__global__ __launch_bounds__(256) void k_prep(
    const float* __restrict__ in, const float* __restrict__ Bre,
    const float* __restrict__ Bim, const float* __restrict__ gamma_log,
    const float* __restrict__ theta, const float* __restrict__ nu,
    unsigned short* __restrict__ A, unsigned short* __restrict__ W,
    float2* __restrict__ lam) {
  int b = blockIdx.x;
  if (b < 4096) {
    int i = b * 256 + threadIdx.x;
    const float4* p = (const float4*)in;
    float4 a = p[2 * i], c = p[2 * i + 1];
    u16x8 o;
    o[0] = f2bf(a.x); o[1] = f2bf(a.y); o[2] = f2bf(a.z); o[3] = f2bf(a.w);
    o[4] = f2bf(c.x); o[5] = f2bf(c.y); o[6] = f2bf(c.z); o[7] = f2bf(c.w);
    *(u16x8*)(A + (size_t)i * 8) = o;
  } else if (b < 5120) {
    int t = (b - 4096) * 256 + threadIdx.x;
    int row = t >> 7;
    int seg = t & 127;
    int k = row >> 1;
    const float* src = (row & 1) ? Bim : Bre;
    float g = expf(gamma_log[k]);
    const float4* p = (const float4*)(src + (size_t)k * D_DIM + seg * 8);
    float4 a = p[0], c = p[1];
    u16x8 o;
    o[0] = f2bf(a.x * g); o[1] = f2bf(a.y * g); o[2] = f2bf(a.z * g); o[3] = f2bf(a.w * g);
    o[4] = f2bf(c.x * g); o[5] = f2bf(c.y * g); o[6] = f2bf(c.z * g); o[7] = f2bf(c.w * g);
    *(u16x8*)(W + (size_t)row * D_DIM + seg * 8) = o;
  } else {
    int k = (b - 5120) * 256 + threadIdx.x;
    if (k < D_DIM) {
      float mod = expf(-expf(nu[k]));
      float ang = expf(theta[k]);
      lam[k] = make_float2(mod * cosf(ang), mod * sinf(ang));
    }
  }
}

// ---------- K2: 256x128 tile, BK=32, 3-buffer ring, 2 blocks/CU + fused agg scan ----------
__global__ __launch_bounds__(512, 4) void k_gemm(const unsigned short* __restrict__ A,
                                                 const unsigned short* __restrict__ W,
                                                 unsigned short* __restrict__ Bu16,
                                                 float2* __restrict__ agg2,
                                                 const float2* __restrict__ lam) {
  extern __shared__ char smem[];   // ring: A bufs [0,48K), B bufs [48K,72K); epilogue 64K

  const int tid = threadIdx.x;
  const int l = tid & 63, w = tid >> 6;
  const int wm = w >> 1, wn = w & 1;          // 4x2 wave grid, 64x64 per wave

  int orig = blockIdx.x;                       // 512 blocks, 8 XCDs, q=64
  int wgid = (orig & 7) * 64 + (orig >> 3);
  const int mt = wgid >> 4, nt = wgid & 15;
  const size_t m0 = (size_t)mt * 256, n0 = (size_t)nt * 128;

  // staging: linear dst (idx*16), linear src (row*2048 + c*16) — coalesced
#define STAGE_A(bb, TT) do {                                                        \
    const char* s_ = (const char*)A + m0 * 2048 + (size_t)(TT) * 64;                \
    char* d_ = smem + (bb) * 16384;                                                 \
    gload_lds16(s_ + (size_t)(tid >> 2) * 2048 + (tid & 3) * 16, d_ + tid * 16);    \
    gload_lds16(s_ + (size_t)(128 + (tid >> 2)) * 2048 + (tid & 3) * 16,            \
                d_ + 8192 + tid * 16);                                              \
  } while (0)
#define STAGE_B(bb, TT) do {                                                        \
    const char* s_ = (const char*)W + n0 * 2048 + (size_t)(TT) * 64;                \
    char* d_ = smem + 49152 + (bb) * 8192;                                          \
    gload_lds16(s_ + (size_t)(tid >> 2) * 2048 + (tid & 3) * 16, d_ + tid * 16);    \
  } while (0)

  int aoff[4], boff[4];
#pragma unroll
  for (int fr = 0; fr < 4; ++fr)
    aoff[fr] = (wm * 64 + fr * 16 + (l & 15)) * 64 + (l >> 4) * 16;
#pragma unroll
  for (int fn = 0; fn < 4; ++fn)
    boff[fn] = (wn * 64 + fn * 16 + (l & 15)) * 64 + (l >> 4) * 16;

  f32x4 acc[4][4];
#pragma unroll
  for (int m = 0; m < 4; ++m)
#pragma unroll
    for (int n = 0; n < 4; ++n) acc[m][n] = (f32x4){0.f, 0.f, 0.f, 0.f};

#define VMCNT3 asm volatile("s_waitcnt vmcnt(3)" ::: "memory")
#define VMCNT0 asm volatile("s_waitcnt vmcnt(0)" ::: "memory")
#define BAR()  do { asm volatile("" ::: "memory"); __builtin_amdgcn_s_barrier(); \
                    asm volatile("" ::: "memory"); } while (0)

  // prologue: stage tiles 0 and 1 (3 loads each per thread)
  STAGE_A(0, 0); STAGE_B(0, 0);
  STAGE_A(1, 1); STAGE_B(1, 1);
  VMCNT3;          // tile 0 resident; tile 1 in flight
  BAR();

  for (int kt = 0; kt < 32; ++kt) {
    const int rb = kt % 3;
    if (kt + 2 < 32) {
      const int nb = (kt + 2) % 3;
      STAGE_A(nb, kt + 2);
      STAGE_B(nb, kt + 2);
    }
    const char* ab = smem + rb * 16384;
    const char* bb = smem + 49152 + rb * 8192;
    bf16x8 a_[4], b_[4];
#pragma unroll
    for (int fr = 0; fr < 4; ++fr) a_[fr] = *(const bf16x8*)(ab + aoff[fr]);
#pragma unroll
    for (int fn = 0; fn < 4; ++fn) b_[fn] = *(const bf16x8*)(bb + boff[fn]);
    __builtin_amdgcn_s_setprio(1);
#pragma unroll
    for (int fr = 0; fr < 4; ++fr)
#pragma unroll
      for (int fn = 0; fn < 4; ++fn)
        acc[fr][fn] = __builtin_amdgcn_mfma_f32_16x16x32_bf16(a_[fr], b_[fn],
                                                              acc[fr][fn], 0, 0, 0);
    __builtin_amdgcn_s_setprio(0);
    if (kt < 30) VMCNT3; else VMCNT0;   // next tile resident before crossing barrier
    BAR();
  }
#undef STAGE_A
#undef STAGE_B

  // ---- epilogue: acc -> LDS bf16 [256 rows][256 B], 16B-chunk XOR swizzle by row&7
#pragma unroll
  for (int fr = 0; fr < 4; ++fr)
#pragma unroll
    for (int fn = 0; fn < 4; ++fn) {
      int col = wn * 64 + fn * 16 + (l & 15);
#pragma unroll
      for (int j = 0; j < 4; ++j) {
        int row = wm * 64 + fr * 16 + (l >> 4) * 4 + j;
        int byte = row * 256 + ((col * 2) ^ ((row & 7) << 4));
        *(unsigned short*)(smem + byte) = f2bf(acc[fr][fn][j]);
      }
    }
  __syncthreads();

  // coalesced bf16 Bu write: 8 passes x 32 rows x 16 chunks
  {
    unsigned short* gbase = Bu16 + m0 * N_COL + n0;
#pragma unroll
    for (int pass = 0; pass < 8; ++pass) {
      int row = pass * 32 + (tid >> 4);
      int c = tid & 15;
      int byte = row * 256 + ((c * 16) ^ ((row & 7) << 4));
      f32x4 v = *(const f32x4*)(smem + byte);
      *(f32x4*)(gbase + (size_t)row * N_COL + c * 8) = v;
    }
  }

  // fused chunk-aggregate scan: 16 chunks x 64 channels; batch reads then chain
#pragma unroll
  for (int i = 0; i < 2; ++i) {
    int q = i * 512 + tid;
    int c = q >> 6, ch = q & 63;
    float2 lmv = lam[(n0 >> 1) + ch];
    unsigned int pr[16];
#pragma unroll
    for (int s = 0; s < 16; ++s) {
      int row = c * 16 + s;
      pr[s] = *(const unsigned int*)(smem + row * 256 + ((ch * 4) ^ ((row & 7) << 4)));
    }
    float2 h = {0.f, 0.f};
#pragma unroll
    for (int s = 0; s < 16; ++s) {
      float br = bf2f((unsigned short)(pr[s] & 0xFFFFu));
      float bi = bf2f((unsigned short)(pr[s] >> 16));
      float nr = fmaf(lmv.x, h.x, fmaf(-lmv.y, h.y, br));
      float ni = fmaf(lmv.x, h.y, fmaf(lmv.y, h.x, bi));
      h.x = nr; h.y = ni;
    }
    agg2[(size_t)(mt * 16 + c) * 1024 + (n0 >> 1) + ch] = h;
  }
}

// ---------- K4: wave-parallel scan of chunk aggregates ----------
__global__ __launch_bounds__(256) void k_scan2(const float4* __restrict__ agg4,
                                               const float4* __restrict__ lam4,
                                               float4* __restrict__ carry4) {
  int wave = blockIdx.x * 4 + (threadIdx.x >> 6);
  int lane = threadIdx.x & 63;
  int j = wave;
  float4 lm = lam4[j];
  float2 lT0 = {lm.x, lm.y}, lT1 = {lm.z, lm.w};
#pragma unroll
  for (int i = 0; i < 4; ++i) { lT0 = csqr(lT0); lT1 = csqr(lT1); }

  float4 a[8];
  float2 T0 = {0.f, 0.f}, T1 = {0.f, 0.f};
  float4 lTv = make_float4(lT0.x, lT0.y, lT1.x, lT1.y);
#pragma unroll
  for (int i = 0; i < 8; ++i) {
    a[i] = agg4[(size_t)(lane * 8 + i) * N_PAIR + j];
    cfma2(lTv, T0, T1, a[i]);
  }

  float2 M0 = lT0, M1 = lT1;
#pragma unroll
  for (int i = 0; i < 3; ++i) { M0 = csqr(M0); M1 = csqr(M1); }
  float2 S0 = T0, S1 = T1;
#pragma unroll
  for (int d = 1; d < 64; d <<= 1) {
    float2 u0, u1;
    u0.x = __shfl_up(S0.x, d); u0.y = __shfl_up(S0.y, d);
    u1.x = __shfl_up(S1.x, d); u1.y = __shfl_up(S1.y, d);
    if (lane >= d) {
      float2 m0 = cmul(M0, u0), m1 = cmul(M1, u1);
      S0.x += m0.x; S0.y += m0.y; S1.x += m1.x; S1.y += m1.y;
    }
    M0 = csqr(M0); M1 = csqr(M1);
  }
  float2 P0, P1;
  P0.x = __shfl_up(S0.x, 1); P0.y = __shfl_up(S0.y, 1);
  P1.x = __shfl_up(S1.x, 1); P1.y = __shfl_up(S1.y, 1);
  if (lane == 0) { P0 = make_float2(0.f, 0.f); P1 = make_float2(0.f, 0.f); }

#pragma unroll
  for (int i = 0; i < 8; ++i) {
    carry4[(size_t)(lane * 8 + i) * N_PAIR + j] = make_float4(P0.x, P0.y, P1.x, P1.y);
    cfma2(lTv, P0, P1, a[i]);
  }
}

// ---------- K5: final rescan + output (bf16 Bu, bf16 inputs) ----------
__global__ __launch_bounds__(256) void k_scan3(const u16x8* __restrict__ Bu8,
                                               const float4* __restrict__ lam4,
                                               const float4* __restrict__ carry4,
                                               const ushort4* __restrict__ inA,
                                               float4* __restrict__ out4) {
  int t = blockIdx.x * 256 + threadIdx.x;
  int c = t >> 8, q = t & 255;
  float4 lm0 = lam4[2 * q], lm1 = lam4[2 * q + 1];
  float4 cv0 = carry4[(size_t)c * N_PAIR + 2 * q];
  float4 cv1 = carry4[(size_t)c * N_PAIR + 2 * q + 1];
  float2 h0 = {cv0.x, cv0.y}, h1 = {cv0.z, cv0.w};
  float2 h2 = {cv1.x, cv1.y}, h3 = {cv1.z, cv1.w};
#pragma unroll
  for (int s = 0; s < CHUNK_T; ++s) {
    size_t row = (size_t)c * CHUNK_T + s;
    u16x8 b = Bu8[row * 256 + q];
    float4 v0 = make_float4(bf2f(b[0]), bf2f(b[1]), bf2f(b[2]), bf2f(b[3]));
    float4 v1 = make_float4(bf2f(b[4]), bf2f(b[5]), bf2f(b[6]), bf2f(b[7]));
    cfma2(lm0, h0, h1, v0);
    cfma2(lm1, h2, h3, v1);
    ushort4 iv = inA[row * 256 + q];
    out4[row * 256 + q] = make_float4(h0.x + bf2f(iv.x), h1.x + bf2f(iv.y),
                                      h2.x + bf2f(iv.z), h3.x + bf2f(iv.w));
  }
}

extern "C" void kernel_launch(void* const* d_in, const int* in_sizes, int n_in,
                              void* d_out, int out_size, void* d_ws, size_t ws_size,
                              hipStream_t stream) {
  (void)in_sizes; (void)n_in; (void)out_size; (void)ws_size;
  const float* inputs    = (const float*)d_in[0];
  const float* theta     = (const float*)d_in[1];
  const float* nu        = (const float*)d_in[2];
  const float* gamma_log = (const float*)d_in[3];
  const float* Bre       = (const float*)d_in[4];
  const float* Bim       = (const float*)d_in[5];

  char* ws = (char*)d_ws;
  float2*         lam   = (float2*)ws;
  unsigned short* A     = (unsigned short*)(ws + (1 << 16));
  unsigned short* W     = (unsigned short*)(ws + (1 << 16) + (16u << 20));
  unsigned short* Bu16  = (unsigned short*)(ws + (1 << 16) + (20u << 20));
  float2*         agg   = (float2*)(ws + (1 << 16) + (52u << 20));
  float4*         carry = (float4*)(ws + (1 << 16) + (56u << 20));

  hipFuncSetAttribute((const void*)k_gemm,
                      hipFuncAttributeMaxDynamicSharedMemorySize, 73728);

  k_prep<<<5124, 256, 0, stream>>>(inputs, Bre, Bim, gamma_log, theta, nu, A, W, lam);
  k_gemm<<<512, 512, 73728, stream>>>(A, W, Bu16, agg, (const float2*)lam);
  k_scan2<<<N_PAIR / 4, 256, 0, stream>>>((const float4*)agg, (const float4*)lam, carry);
  k_scan3<<<(N_CHUNK * 256) / 256, 256, 0, stream>>>((const u16x8*)Bu16,
                                                     (const float4*)lam, carry,
                                                     (const ushort4*)A,
                                                     (float4*)d_out);
}

// Round 11
// 73.710 us; speedup vs baseline: 1.0119x; 1.0119x over previous
//
#include <hip/hip_runtime.h>
#include <cstdint>
#include <cstddef>

typedef float  f32x4   __attribute__((ext_vector_type(4)));
typedef short  bf16x8  __attribute__((ext_vector_type(8)));
typedef unsigned short u16x8 __attribute__((ext_vector_type(8)));

#define L_SEQ   8192
#define D_DIM   1024
#define N_COL   2048
#define N_PAIR  512
#define CHUNK_T 16
#define N_CHUNK 512

__device__ __forceinline__ unsigned short f2bf(float f) {
  unsigned int b = __float_as_uint(f);
  b += 0x7FFFu + ((b >> 16) & 1u);
  return (unsigned short)(b >> 16);
}
__device__ __forceinline__ float bf2f(unsigned short u) {
  return __uint_as_float((unsigned int)u << 16);
}
__device__ __forceinline__ void gload_lds16(const void* g, void* lds) {
  __builtin_amdgcn_global_load_lds(
      (const __attribute__((address_space(1))) void*)g,
      (__attribute__((address_space(3))) void*)lds, 16, 0, 0);
}
__device__ __forceinline__ float2 cmul(float2 a, float2 b) {
  return make_float2(a.x * b.x - a.y * b.y, a.x * b.y + a.y * b.x);
}
__device__ __forceinline__ float2 csqr(float2 a) {
  return make_float2(a.x * a.x - a.y * a.y, 2.f * a.x * a.y);
}
__device__ __forceinline__ void cfma2(const float4& lm, float2& h0, float2& h1,
                                      const float4& v) {
  float nr0 = fmaf(lm.x, h0.x, fmaf(-lm.y, h0.y, v.x));
  float ni0 = fmaf(lm.x, h0.y, fmaf(lm.y, h0.x, v.y));
  float nr1 = fmaf(lm.z, h1.x, fmaf(-lm.w, h1.y, v.z));
  float ni1 = fmaf(lm.z, h1.y, fmaf(lm.w, h1.x, v.w));
  h0.x = nr0; h0.y = ni0; h1.x = nr1; h1.y = ni1;
}

// ---------- K1: fused prep ----------
__global__ __launch_bounds__(256) void k_prep(
    const float* __restrict__ in, const float* __restrict__ Bre,
    const float* __restrict__ Bim, const float* __restrict__ gamma_log,
    const float* __restrict__ theta, const float* __restrict__ nu,
    unsigned short* __restrict__ A, unsigned short* __restrict__ W,
    float2* __restrict__ lam) {
  int b = blockIdx.x;
  if (b < 4096) {
    int i = b * 256 + threadIdx.x;
    const float4* p = (const float4*)in;
    float4 a = p[2 * i], c = p[2 * i + 1];
    u16x8 o;
    o[0] = f2bf(a.x); o[1] = f2bf(a.y); o[2] = f2bf(a.z); o[3] = f2bf(a.w);
    o[4] = f2bf(c.x); o[5] = f2bf(c.y); o[6] = f2bf(c.z); o[7] = f2bf(c.w);
    *(u16x8*)(A + (size_t)i * 8) = o;
  } else if (b < 5120) {
    int t = (b - 4096) * 256 + threadIdx.x;
    int row = t >> 7;
    int seg = t & 127;
    int k = row >> 1;
    const float* src = (row & 1) ? Bim : Bre;
    float g = expf(gamma_log[k]);
    const float4* p = (const float4*)(src + (size_t)k * D_DIM + seg * 8);
    float4 a = p[0], c = p[1];
    u16x8 o;
    o[0] = f2bf(a.x * g); o[1] = f2bf(a.y * g); o[2] = f2bf(a.z * g); o[3] = f2bf(a.w * g);
    o[4] = f2bf(c.x * g); o[5] = f2bf(c.y * g); o[6] = f2bf(c.z * g); o[7] = f2bf(c.w * g);
    *(u16x8*)(W + (size_t)row * D_DIM + seg * 8) = o;
  } else {
    int k = (b - 5120) * 256 + threadIdx.x;
    if (k < D_DIM) {
      float mod = expf(-expf(nu[k]));
      float ang = expf(theta[k]);
      lam[k] = make_float2(mod * cosf(ang), mod * sinf(ang));
    }
  }
}

// ---------- K2: 256x128 tile, BK=32, 4 waves, 3-ring, 2 blocks/CU, bank-fixed ----------
__global__ __launch_bounds__(256, 2) void k_gemm(const unsigned short* __restrict__ A,
                                                 const unsigned short* __restrict__ W,
                                                 unsigned short* __restrict__ Bu16,
                                                 float2* __restrict__ agg2,
                                                 const float2* __restrict__ lam) {
  extern __shared__ char smem[];   // ring: A [0,48K) 3x16K, B [48K,72K) 3x8K; epilogue 64K

  const int tid = threadIdx.x;
  const int l = tid & 63, w = tid >> 6;
  const int wm = w >> 1, wn = w & 1;          // 2x2 wave grid, 128x64 per wave

  int orig = blockIdx.x;                       // 512 blocks, 8 XCDs, q=64
  int wgid = (orig & 7) * 64 + (orig >> 3);
  const int mt = wgid >> 4, nt = wgid & 15;
  const size_t m0 = (size_t)mt * 256, n0 = (size_t)nt * 128;

  // staging: slot s=(p*256+tid): row=p*64+(tid>>2), stored-chunk=tid&3 holds
  // logical chunk (tid&3)^((row>>1)&3) = (tid&3)^((tid>>3)&3)  [p*64 even in &3 after >>1]
  const int sch = (tid & 3) ^ ((tid >> 3) & 3);
  const size_t soff = (size_t)(tid >> 2) * 2048 + (size_t)sch * 16;

#define STAGE(bb, TT) do {                                                          \
    const char* sa = (const char*)A + m0 * 2048 + (size_t)(TT) * 64;                \
    char* da = smem + (bb) * 16384;                                                 \
    gload_lds16(sa + soff,          da + tid * 16);                                 \
    gload_lds16(sa + 131072 + soff, da + 4096 + tid * 16);                          \
    gload_lds16(sa + 262144 + soff, da + 8192 + tid * 16);                          \
    gload_lds16(sa + 393216 + soff, da + 12288 + tid * 16);                         \
    const char* sb = (const char*)W + n0 * 2048 + (size_t)(TT) * 64;                \
    char* db = smem + 49152 + (bb) * 8192;                                          \
    gload_lds16(sb + soff,          db + tid * 16);                                 \
    gload_lds16(sb + 131072 + soff, db + 4096 + tid * 16);                          \
  } while (0)

  // fragment reads: byte = row*64 + ((l>>4)^((row>>1)&3))*16 ; row≡(l&15) mod 16
  const int swk = (((l >> 4)) ^ ((l >> 1) & 3)) << 4;
  int aoff[8], boff[4];
#pragma unroll
  for (int fr = 0; fr < 8; ++fr)
    aoff[fr] = (wm * 128 + fr * 16 + (l & 15)) * 64 + swk;
#pragma unroll
  for (int fn = 0; fn < 4; ++fn)
    boff[fn] = (wn * 64 + fn * 16 + (l & 15)) * 64 + swk;

  f32x4 acc[8][4];
#pragma unroll
  for (int m = 0; m < 8; ++m)
#pragma unroll
    for (int n = 0; n < 4; ++n) acc[m][n] = (f32x4){0.f, 0.f, 0.f, 0.f};

#define VMCNT6 asm volatile("s_waitcnt vmcnt(6)" ::: "memory")
#define VMCNT0 asm volatile("s_waitcnt vmcnt(0)" ::: "memory")
#define BAR()  do { asm volatile("" ::: "memory"); __builtin_amdgcn_s_barrier(); \
                    asm volatile("" ::: "memory"); } while (0)

  // prologue: stage tiles 0,1
  STAGE(0, 0);
  STAGE(1, 1);
  VMCNT6;          // tile 0 resident; tile 1 in flight
  BAR();

  for (int kt = 0; kt < 32; ++kt) {
    const int rb = kt % 3;
    if (kt + 2 < 32) STAGE((kt + 2) % 3, kt + 2);
    const char* ab = smem + rb * 16384;
    const char* bb = smem + 49152 + rb * 8192;
    bf16x8 a_[8], b_[4];
#pragma unroll
    for (int fr = 0; fr < 8; ++fr) a_[fr] = *(const bf16x8*)(ab + aoff[fr]);
#pragma unroll
    for (int fn = 0; fn < 4; ++fn) b_[fn] = *(const bf16x8*)(bb + boff[fn]);
    __builtin_amdgcn_s_setprio(1);
#pragma unroll
    for (int fr = 0; fr < 8; ++fr)
#pragma unroll
      for (int fn = 0; fn < 4; ++fn)
        acc[fr][fn] = __builtin_amdgcn_mfma_f32_16x16x32_bf16(a_[fr], b_[fn],
                                                              acc[fr][fn], 0, 0, 0);
    __builtin_amdgcn_s_setprio(0);
    if (kt < 30) VMCNT6; else VMCNT0;   // next tile resident before crossing barrier
    BAR();
  }
#undef STAGE

  // ---- epilogue: acc -> LDS bf16 [256 rows][256 B], 16B-chunk XOR swizzle by row&7
#pragma unroll
  for (int fr = 0; fr < 8; ++fr)
#pragma unroll
    for (int fn = 0; fn < 4; ++fn) {
      int col = wn * 64 + fn * 16 + (l & 15);
#pragma unroll
      for (int j = 0; j < 4; ++j) {
        int row = wm * 128 + fr * 16 + (l >> 4) * 4 + j;
        int byte = row * 256 + ((col * 2) ^ ((row & 7) << 4));
        *(unsigned short*)(smem + byte) = f2bf(acc[fr][fn][j]);
      }
    }
  __syncthreads();

  // coalesced bf16 Bu write: 16 passes x 16 rows x 16 chunks
  {
    unsigned short* gbase = Bu16 + m0 * N_COL + n0;
#pragma unroll
    for (int pass = 0; pass < 16; ++pass) {
      int row = pass * 16 + (tid >> 4);
      int c = tid & 15;
      int byte = row * 256 + ((c * 16) ^ ((row & 7) << 4));
      f32x4 v = *(const f32x4*)(smem + byte);
      *(f32x4*)(gbase + (size_t)row * N_COL + c * 8) = v;
    }
  }

  // fused chunk-aggregate scan: 16 chunks x 64 channels; batch reads then chain
#pragma unroll
  for (int i = 0; i < 4; ++i) {
    int q = i * 256 + tid;
    int c = q >> 6, ch = q & 63;
    float2 lmv = lam[(n0 >> 1) + ch];
    unsigned int pr[16];
#pragma unroll
    for (int s = 0; s < 16; ++s) {
      int row = c * 16 + s;
      pr[s] = *(const unsigned int*)(smem + row * 256 + ((ch * 4) ^ ((row & 7) << 4)));
    }
    float2 h = {0.f, 0.f};
#pragma unroll
    for (int s = 0; s < 16; ++s) {
      float br = bf2f((unsigned short)(pr[s] & 0xFFFFu));
      float bi = bf2f((unsigned short)(pr[s] >> 16));
      float nr = fmaf(lmv.x, h.x, fmaf(-lmv.y, h.y, br));
      float ni = fmaf(lmv.x, h.y, fmaf(lmv.y, h.x, bi));
      h.x = nr; h.y = ni;
    }
    agg2[(size_t)(mt * 16 + c) * 1024 + (n0 >> 1) + ch] = h;
  }
}

// ---------- K4: wave-parallel scan of chunk aggregates ----------
__global__ __launch_bounds__(256) void k_scan2(const float4* __restrict__ agg4,
                                               const float4* __restrict__ lam4,
                                               float4* __restrict__ carry4) {
  int wave = blockIdx.x * 4 + (threadIdx.x >> 6);
  int lane = threadIdx.x & 63;
  int j = wave;
  float4 lm = lam4[j];
  float2 lT0 = {lm.x, lm.y}, lT1 = {lm.z, lm.w};
#pragma unroll
  for (int i = 0; i < 4; ++i) { lT0 = csqr(lT0); lT1 = csqr(lT1); }

  float4 a[8];
  float2 T0 = {0.f, 0.f}, T1 = {0.f, 0.f};
  float4 lTv = make_float4(lT0.x, lT0.y, lT1.x, lT1.y);
#pragma unroll
  for (int i = 0; i < 8; ++i) {
    a[i] = agg4[(size_t)(lane * 8 + i) * N_PAIR + j];
    cfma2(lTv, T0, T1, a[i]);
  }

  float2 M0 = lT0, M1 = lT1;
#pragma unroll
  for (int i = 0; i < 3; ++i) { M0 = csqr(M0); M1 = csqr(M1); }
  float2 S0 = T0, S1 = T1;
#pragma unroll
  for (int d = 1; d < 64; d <<= 1) {
    float2 u0, u1;
    u0.x = __shfl_up(S0.x, d); u0.y = __shfl_up(S0.y, d);
    u1.x = __shfl_up(S1.x, d); u1.y = __shfl_up(S1.y, d);
    if (lane >= d) {
      float2 m0 = cmul(M0, u0), m1 = cmul(M1, u1);
      S0.x += m0.x; S0.y += m0.y; S1.x += m1.x; S1.y += m1.y;
    }
    M0 = csqr(M0); M1 = csqr(M1);
  }
  float2 P0, P1;
  P0.x = __shfl_up(S0.x, 1); P0.y = __shfl_up(S0.y, 1);
  P1.x = __shfl_up(S1.x, 1); P1.y = __shfl_up(S1.y, 1);
  if (lane == 0) { P0 = make_float2(0.f, 0.f); P1 = make_float2(0.f, 0.f); }

#pragma unroll
  for (int i = 0; i < 8; ++i) {
    carry4[(size_t)(lane * 8 + i) * N_PAIR + j] = make_float4(P0.x, P0.y, P1.x, P1.y);
    cfma2(lTv, P0, P1, a[i]);
  }
}

// ---------- K5: final rescan + output (bf16 Bu, bf16 inputs) ----------
__global__ __launch_bounds__(256) void k_scan3(const u16x8* __restrict__ Bu8,
                                               const float4* __restrict__ lam4,
                                               const float4* __restrict__ carry4,
                                               const ushort4* __restrict__ inA,
                                               float4* __restrict__ out4) {
  int t = blockIdx.x * 256 + threadIdx.x;
  int c = t >> 8, q = t & 255;
  float4 lm0 = lam4[2 * q], lm1 = lam4[2 * q + 1];
  float4 cv0 = carry4[(size_t)c * N_PAIR + 2 * q];
  float4 cv1 = carry4[(size_t)c * N_PAIR + 2 * q + 1];
  float2 h0 = {cv0.x, cv0.y}, h1 = {cv0.z, cv0.w};
  float2 h2 = {cv1.x, cv1.y}, h3 = {cv1.z, cv1.w};
#pragma unroll
  for (int s = 0; s < CHUNK_T; ++s) {
    size_t row = (size_t)c * CHUNK_T + s;
    u16x8 b = Bu8[row * 256 + q];
    float4 v0 = make_float4(bf2f(b[0]), bf2f(b[1]), bf2f(b[2]), bf2f(b[3]));
    float4 v1 = make_float4(bf2f(b[4]), bf2f(b[5]), bf2f(b[6]), bf2f(b[7]));
    cfma2(lm0, h0, h1, v0);
    cfma2(lm1, h2, h3, v1);
    ushort4 iv = inA[row * 256 + q];
    out4[row * 256 + q] = make_float4(h0.x + bf2f(iv.x), h1.x + bf2f(iv.y),
                                      h2.x + bf2f(iv.z), h3.x + bf2f(iv.w));
  }
}

extern "C" void kernel_launch(void* const* d_in, const int* in_sizes, int n_in,
                              void* d_out, int out_size, void* d_ws, size_t ws_size,
                              hipStream_t stream) {
  (void)in_sizes; (void)n_in; (void)out_size; (void)ws_size;
  const float* inputs    = (const float*)d_in[0];
  const float* theta     = (const float*)d_in[1];
  const float* nu        = (const float*)d_in[2];
  const float* gamma_log = (const float*)d_in[3];
  const float* Bre       = (const float*)d_in[4];
  const float* Bim       = (const float*)d_in[5];

  char* ws = (char*)d_ws;
  float2*         lam   = (float2*)ws;
  unsigned short* A     = (unsigned short*)(ws + (1 << 16));
  unsigned short* W     = (unsigned short*)(ws + (1 << 16) + (16u << 20));
  unsigned short* Bu16  = (unsigned short*)(ws + (1 << 16) + (20u << 20));
  float2*         agg   = (float2*)(ws + (1 << 16) + (52u << 20));
  float4*         carry = (float4*)(ws + (1 << 16) + (56u << 20));

  hipFuncSetAttribute((const void*)k_gemm,
                      hipFuncAttributeMaxDynamicSharedMemorySize, 73728);

  k_prep<<<5124, 256, 0, stream>>>(inputs, Bre, Bim, gamma_log, theta, nu, A, W, lam);
  k_gemm<<<512, 256, 73728, stream>>>(A, W, Bu16, agg, (const float2*)lam);
  k_scan2<<<N_PAIR / 4, 256, 0, stream>>>((const float4*)agg, (const float4*)lam, carry);
  k_scan3<<<(N_CHUNK * 256) / 256, 256, 0, stream>>>((const u16x8*)Bu16,
                                                     (const float4*)lam, carry,
                                                     (const ushort4*)A,
                                                     (float4*)d_out);
}